// Round 3
// baseline (7285.899 us; speedup 1.0000x reference)
//
#include <hip/hip_runtime.h>
#include <hip/hip_fp16.h>

// Problem dims
#define BB   128
#define TT   512
#define INS  64
#define HH   512
#define K0   576    // INS + HH (layer0 fused [x | h1] GEMM depth)
#define K1   1024   // HH + HH  (layer1 fused [h1 | h2] GEMM depth)
#define PAD0 584    // K0 + 8 (LDS pad, keeps 16B alignment)
#define PAD1 1032   // K1 + 8
#define NWG  128
#define NTHR 512
#define H2   256

typedef _Float16 f16;
typedef f16 f16x4 __attribute__((ext_vector_type(4)));
typedef f16 f16x8 __attribute__((ext_vector_type(8)));
typedef float f32x4 __attribute__((ext_vector_type(4)));

__device__ __forceinline__ float sigmoidf_(float x) {
  return 1.0f / (1.0f + __expf(-x));
}
__device__ __forceinline__ float tanhf_(float x) {
  return 1.0f - 2.0f / (__expf(2.0f * x) + 1.0f);
}

// Coherent (LLC-visible, L2-bypassing) h access: relaxed agent-scope atomics.
// These compile to global_load/store with sc1 — no cache-wide fences needed.
__device__ __forceinline__ f16x8 ldg_h(const f16* p) {
  union { unsigned long long q[2]; f16x8 v; } u;
  const unsigned long long* qp = (const unsigned long long*)p;
  u.q[0] = __hip_atomic_load(qp,     __ATOMIC_RELAXED, __HIP_MEMORY_SCOPE_AGENT);
  u.q[1] = __hip_atomic_load(qp + 1, __ATOMIC_RELAXED, __HIP_MEMORY_SCOPE_AGENT);
  return u.v;
}
__device__ __forceinline__ void stg_h(f16* p, unsigned int pk) {
  __hip_atomic_store((unsigned int*)p, pk, __ATOMIC_RELAXED, __HIP_MEMORY_SCOPE_AGENT);
}

// Persistent fused 2-layer LSTM.
// Grid: 128 WGs x 512 threads (8 waves). WG = (mg 0..1, ng 0..63):
// owns M-rows mg*64..+64 and h-columns ng*8..+8 (-> 32 gate rows), both layers.
// waves 0-3 -> layer0 (16 rows each), waves 4-7 -> layer1.
// The two mg halves are fully independent (separate barriers, disjoint h rows).
// Superstep s: L0 computes h1_s (s<T), L1 computes h2_{s-1} (s>=1). 513 supersteps.
__global__ __launch_bounds__(NTHR, 1) void lstm_fused(
    const float* __restrict__ x,
    const float* __restrict__ Wih0, const float* __restrict__ Whh0,
    const float* __restrict__ bih0, const float* __restrict__ bhh0,
    const float* __restrict__ Wih1, const float* __restrict__ Whh1,
    const float* __restrict__ bih1, const float* __restrict__ bhh1,
    int* __restrict__ bar, f16* __restrict__ h1buf, f16* __restrict__ h2buf)
{
  extern __shared__ f16 smem[];
  f16* W0s = smem;                 // [32][PAD0]
  f16* W1s = smem + 32 * PAD0;     // [32][PAD1]

  const int tid  = threadIdx.x;
  const int wg   = blockIdx.x;
  const int mg   = wg >> 6;
  const int ng   = wg & 63;
  const int wid  = tid >> 6;
  const int lane = tid & 63;

  // ---- weights -> LDS (fp16), vectorized float4, once ----
  // LDS row r = q*8+j -> global gate row g = q*512 + ng*8 + j (q: 0=i,1=f,2=g,3=o)
  for (int e4 = tid; e4 < 32 * (K0 / 4); e4 += NTHR) {
    int r = e4 / (K0 / 4), k = (e4 - r * (K0 / 4)) * 4;
    int g = ((r >> 3) << 9) + (ng << 3) + (r & 7);
    float4 v = (k < INS)
        ? *reinterpret_cast<const float4*>(Wih0 + g * INS + k)
        : *reinterpret_cast<const float4*>(Whh0 + g * HH + (k - INS));
    f16x4 h; h[0]=(f16)v.x; h[1]=(f16)v.y; h[2]=(f16)v.z; h[3]=(f16)v.w;
    *reinterpret_cast<f16x4*>(&W0s[r * PAD0 + k]) = h;
  }
  for (int e4 = tid; e4 < 32 * (K1 / 4); e4 += NTHR) {
    int r = e4 >> 8, k = (e4 & 255) * 4;
    int g = ((r >> 3) << 9) + (ng << 3) + (r & 7);
    float4 v = (k < HH)
        ? *reinterpret_cast<const float4*>(Wih1 + g * HH + k)
        : *reinterpret_cast<const float4*>(Whh1 + g * HH + (k - HH));
    f16x4 h; h[0]=(f16)v.x; h[1]=(f16)v.y; h[2]=(f16)v.z; h[3]=(f16)v.w;
    *reinterpret_cast<f16x4*>(&W1s[r * PAD1 + k]) = h;
  }

  const bool isL1 = (wid >= 4);
  const int  wrow = mg * 64 + (wid & 3) * 16;   // wave M base (16 rows)
  const int  col0 = lane & 15;        // fragment column (gate col within frag)
  const int  rA   = lane & 15;        // A-row within fragment
  const int  kq   = (lane >> 4) * 8;  // k sub-offset within a 32-wide k-step
  const int  hcol = (ng << 3) + (lane & 7);
  const bool low  = (lane & 8) == 0;  // lanes holding i (frag0) / g (frag1)
  const bool evn  = (lane & 1) == 0;

  float bias[2];
  #pragma unroll
  for (int n = 0; n < 2; n++) {
    int c = n * 16 + col0;
    int g = ((c >> 3) << 9) + (ng << 3) + (c & 7);
    bias[n] = isL1 ? (bih1[g] + bhh1[g]) : (bih0[g] + bhh0[g]);
  }
  __syncthreads();

  f32x4 cst = {};  // cell state (4 rows x 1 col per low lane)

  // per-half barrier region (monotonic counters, no resets):
  // 8 group lines (8 WGs each) + glob + gen; half stride 1024 dwords (4KB)
  int* barh = bar + mg * 1024;
  int* grp  = barh + (ng & 7) * 64;
  int* glob = barh + 512;
  int* genp = barh + 576;

  for (int s = 0; s <= TT; ++s) {
    const f16* h1r = h1buf + ((s + 1) & 1) * (BB * HH); // h1_{s-1}
    f16*       h1w = h1buf + ((s    ) & 1) * (BB * HH); // h1_s
    const f16* h2r = h2buf + ((s    ) & 1) * (BB * HH); // h2_{s-2}
    f16*       h2w = h2buf + ((s + 1) & 1) * (BB * HH); // h2_{s-1}

    const bool active = isL1 ? (s >= 1) : (s < TT);
    if (active) {
      const int row = wrow + rA;
      f32x4 acc0 = {}, acc1 = {};

      if (!isL1) {
        // ---- layer0: gates = [x_s | h1_{s-1}] @ [Wih0 | Whh0]^T ----
        const float* xb = x + ((size_t)row * TT + (size_t)s) * INS;
        #pragma unroll
        for (int ks = 0; ks < 2; ++ks) {
          const int kk = ks * 32 + kq;
          float4 q0 = *reinterpret_cast<const float4*>(xb + kk);
          float4 q1 = *reinterpret_cast<const float4*>(xb + kk + 4);
          f16x8 a;
          a[0]=(f16)q0.x; a[1]=(f16)q0.y; a[2]=(f16)q0.z; a[3]=(f16)q0.w;
          a[4]=(f16)q1.x; a[5]=(f16)q1.y; a[6]=(f16)q1.z; a[7]=(f16)q1.w;
          f16x8 b0 = *reinterpret_cast<const f16x8*>(&W0s[col0 * PAD0 + kk]);
          f16x8 b1 = *reinterpret_cast<const f16x8*>(&W0s[(16 + col0) * PAD0 + kk]);
          acc0 = __builtin_amdgcn_mfma_f32_16x16x32_f16(a, b0, acc0, 0, 0, 0);
          acc1 = __builtin_amdgcn_mfma_f32_16x16x32_f16(a, b1, acc1, 0, 0, 0);
        }
        #pragma unroll
        for (int c = 0; c < 2; ++c) {
          f16x8 a[8];
          #pragma unroll
          for (int u = 0; u < 8; ++u) {
            const int kh = (c * 8 + u) * 32 + kq;
            a[u] = ldg_h(h1r + row * HH + kh);
          }
          #pragma unroll
          for (int u = 0; u < 8; ++u) {
            const int kk = INS + (c * 8 + u) * 32 + kq;
            f16x8 b0 = *reinterpret_cast<const f16x8*>(&W0s[col0 * PAD0 + kk]);
            f16x8 b1 = *reinterpret_cast<const f16x8*>(&W0s[(16 + col0) * PAD0 + kk]);
            acc0 = __builtin_amdgcn_mfma_f32_16x16x32_f16(a[u], b0, acc0, 0, 0, 0);
            acc1 = __builtin_amdgcn_mfma_f32_16x16x32_f16(a[u], b1, acc1, 0, 0, 0);
          }
        }
      } else {
        // ---- layer1: gates = [h1_{s-1} | h2_{s-2}] @ [Wih1 | Whh1]^T ----
        #pragma unroll
        for (int c = 0; c < 4; ++c) {
          f16x8 a[8];
          #pragma unroll
          for (int u = 0; u < 8; ++u) {
            const int kk = (c * 8 + u) * 32 + kq;
            a[u] = (c < 2) ? ldg_h(h1r + row * HH + kk)
                           : ldg_h(h2r + row * HH + (kk - HH));
          }
          #pragma unroll
          for (int u = 0; u < 8; ++u) {
            const int kk = (c * 8 + u) * 32 + kq;
            f16x8 b0 = *reinterpret_cast<const f16x8*>(&W1s[col0 * PAD1 + kk]);
            f16x8 b1 = *reinterpret_cast<const f16x8*>(&W1s[(16 + col0) * PAD1 + kk]);
            acc0 = __builtin_amdgcn_mfma_f32_16x16x32_f16(a[u], b0, acc0, 0, 0, 0);
            acc1 = __builtin_amdgcn_mfma_f32_16x16x32_f16(a[u], b1, acc1, 0, 0, 0);
          }
        }
      }

      // ---- LSTM cell (frag0 = [i|f], frag1 = [g|o]) ----
      float res[4];
      #pragma unroll
      for (int j = 0; j < 4; j++) {
        float v0 = acc0[j] + bias[0];
        float v1 = acc1[j] + bias[1];
        float p0 = __shfl_xor(v0, 8, 64);
        float p1 = __shfl_xor(v1, 8, 64);
        float ip = low ? v0 : p0;
        float fp = low ? p0 : v0;
        float gp = low ? v1 : p1;
        float op = low ? p1 : v1;
        float cn = sigmoidf_(fp) * cst[j] + sigmoidf_(ip) * tanhf_(gp);
        cst[j] = cn;
        res[j] = sigmoidf_(op) * tanhf_(cn);
      }
      {
        f16* hw = isL1 ? h2w : h1w;
        const int rowb = wrow + ((lane >> 4) << 2);
        #pragma unroll
        for (int j = 0; j < 4; j++) {
          float other = __shfl_xor(res[j], 1, 64);  // partner col (hcol^1)
          if (low && evn) {
            f16 lo_ = (f16)res[j], hi_ = (f16)other;
            unsigned int pk =
                (unsigned int)__builtin_bit_cast(unsigned short, lo_) |
                ((unsigned int)__builtin_bit_cast(unsigned short, hi_) << 16);
            stg_h(hw + (rowb + j) * HH + hcol, pk);
          }
        }
      }
    }

    // ---- grid barrier: per-half, fence-free, monotonic counters ----
    asm volatile("s_waitcnt vmcnt(0)" ::: "memory");  // h stores at LLC (sc1)
    __syncthreads();
    if (tid == 0) {
      int p = __hip_atomic_fetch_add(grp, 1, __ATOMIC_RELAXED, __HIP_MEMORY_SCOPE_AGENT);
      if ((p & 7) == 7) {
        int q = __hip_atomic_fetch_add(glob, 1, __ATOMIC_RELAXED, __HIP_MEMORY_SCOPE_AGENT);
        if ((q & 7) == 7)
          __hip_atomic_fetch_add(genp, 1, __ATOMIC_RELAXED, __HIP_MEMORY_SCOPE_AGENT);
      }
      while (__hip_atomic_load(genp, __ATOMIC_RELAXED, __HIP_MEMORY_SCOPE_AGENT) < s + 1)
        __builtin_amdgcn_s_sleep(1);
      asm volatile("" ::: "memory");
    }
    __syncthreads();
  }
}

__global__ void fc1_kernel(const f16* __restrict__ last, const float* __restrict__ w,
                           const float* __restrict__ b, float* __restrict__ z) {
  const int bb = blockIdx.x;   // batch row
  const int j  = threadIdx.x;  // 0..255 output col
  const f16*   lp = last + bb * HH;
  const float* wp = w + j * HH;
  float s = b[j];
  #pragma unroll 8
  for (int k = 0; k < HH; k++) s += (float)lp[k] * wp[k];
  z[bb * H2 + j] = fmaxf(s, 0.0f);
}

__global__ void fc2_kernel(const float* __restrict__ z, const float* __restrict__ w,
                           const float* __restrict__ b, float* __restrict__ out) {
  const int bb = threadIdx.x;  // 0..127
  float s = b[0];
  #pragma unroll 8
  for (int k = 0; k < H2; k++) s += z[bb * H2 + k] * w[k];
  out[bb] = s;
}

extern "C" void kernel_launch(void* const* d_in, const int* in_sizes, int n_in,
                              void* d_out, int out_size, void* d_ws, size_t ws_size,
                              hipStream_t stream) {
  const float* x     = (const float*)d_in[0];
  const float* Wih0  = (const float*)d_in[1];
  const float* Whh0  = (const float*)d_in[2];
  const float* bih0  = (const float*)d_in[3];
  const float* bhh0  = (const float*)d_in[4];
  const float* Wih1  = (const float*)d_in[5];
  const float* Whh1  = (const float*)d_in[6];
  const float* bih1  = (const float*)d_in[7];
  const float* bhh1  = (const float*)d_in[8];
  const float* fc1w  = (const float*)d_in[9];
  const float* fc1b  = (const float*)d_in[10];
  const float* fc2w  = (const float*)d_in[11];
  const float* fc2b  = (const float*)d_in[12];

  char* ws = (char*)d_ws;
  int*  bar = (int*)ws;                          // 8 KB barrier region (2 halves)
  f16*  h1  = (f16*)(ws + 8192);                 // 2 x B x H
  f16*  h2  = h1 + 2 * BB * HH;                  // 2 x B x H
  float* z  = (float*)(ws + 8192 + (size_t)4 * BB * HH * sizeof(f16));  // B x H2

  // zero barrier + h buffers (h_{-1} = 0); re-run every replay
  hipMemsetAsync(ws, 0, 8192 + (size_t)4 * BB * HH * sizeof(f16), stream);

  const size_t smem = (size_t)(32 * PAD0 + 32 * PAD1) * sizeof(f16);
  lstm_fused<<<NWG, NTHR, smem, stream>>>(x, Wih0, Whh0, bih0, bhh0,
                                          Wih1, Whh1, bih1, bhh1, bar, h1, h2);

  const f16* last = h2 + ((TT - 1) & 1) * (BB * HH);  // h2_{T-1}
  fc1_kernel<<<BB, 256, 0, stream>>>(last, fc1w, fc1b, z);
  fc2_kernel<<<1, BB, 0, stream>>>(z, fc2w, fc2b, (float*)d_out);
}